// Round 1
// baseline (373.819 us; speedup 1.0000x reference)
//
#include <hip/hip_runtime.h>
#include <cstdint>

#define D_MODEL 1024
#define HIDDEN  4096
#define BATCH   4
#define SEQ     2048
#define NROWS   (BATCH*SEQ)   // 8192

typedef __attribute__((ext_vector_type(8))) __bf16 bf16x8;
typedef __attribute__((ext_vector_type(4))) float f32x4;

__device__ __forceinline__ unsigned short f2bf(float f) {
  union { float f; unsigned u; } a; a.f = f;
  unsigned u = a.u;
  u += 0x7fffu + ((u >> 16) & 1u);   // round-to-nearest-even
  return (unsigned short)(u >> 16);
}

__device__ __forceinline__ float block_sum(float v, float* s4) {
  #pragma unroll
  for (int off = 32; off > 0; off >>= 1) v += __shfl_down(v, off);
  int lane = threadIdx.x & 63, wid = threadIdx.x >> 6;
  __syncthreads();
  if (lane == 0) s4[wid] = v;
  __syncthreads();
  return s4[0] + s4[1] + s4[2] + s4[3];
}

// ---- transpose + f32->bf16 convert: in [R][C] f32 -> out [C][R] bf16 ----
__global__ __launch_bounds__(256) void transpose_cvt(
    const float* __restrict__ in, unsigned short* __restrict__ out, int R, int C) {
  __shared__ float tile[32][33];
  int c0 = blockIdx.x * 32, r0 = blockIdx.y * 32;
  int tx = threadIdx.x & 31, ty = threadIdx.x >> 5;   // ty 0..7
  #pragma unroll
  for (int i = ty; i < 32; i += 8)
    tile[i][tx] = in[(size_t)(r0 + i) * C + c0 + tx];
  __syncthreads();
  #pragma unroll
  for (int i = ty; i < 32; i += 8)
    out[(size_t)(c0 + i) * R + r0 + tx] = f2bf(tile[tx][i]);
}

// ---- LN1 of row s=0 of each batch -> h0 [B][D] f32 ----
__global__ __launch_bounds__(256) void ln_row0_kernel(
    const float* __restrict__ x, const float* __restrict__ g,
    const float* __restrict__ be, float* __restrict__ h0) {
  __shared__ float s4[4];
  int b = blockIdx.x;
  const float* xr = x + (size_t)b * SEQ * D_MODEL;
  int t = threadIdx.x;
  float v[4]; float sum = 0.f;
  #pragma unroll
  for (int i = 0; i < 4; ++i) { v[i] = xr[t + i * 256]; sum += v[i]; }
  float mean = block_sum(sum, s4) * (1.f / 1024.f);
  float sq = 0.f;
  #pragma unroll
  for (int i = 0; i < 4; ++i) { float c = v[i] - mean; sq += c * c; }
  float var = block_sum(sq, s4) * (1.f / 1023.f);   // ddof=1
  float inv = 1.f / (sqrtf(var) + 1e-6f);           // eps on std
  #pragma unroll
  for (int i = 0; i < 4; ++i) {
    int d = t + i * 256;
    h0[b * D_MODEL + d] = g[d] * (v[i] - mean) * inv + be[d];
  }
}

// ---- vout[b][n] = sum_k vin[b][k] * W[k][n], 4 batches per block ----
__global__ __launch_bounds__(256) void matvec_b4(
    const float* __restrict__ vin, const float* __restrict__ W,
    float* __restrict__ vout) {
  __shared__ float hs[4][D_MODEL];
  int n = blockIdx.x * 256 + threadIdx.x;
  for (int i = threadIdx.x; i < 4 * D_MODEL; i += 256)
    hs[i >> 10][i & (D_MODEL - 1)] = vin[i];
  __syncthreads();
  float a0 = 0, a1 = 0, a2 = 0, a3 = 0;
  for (int k = 0; k < D_MODEL; ++k) {
    float w = W[(size_t)k * D_MODEL + n];
    a0 = fmaf(hs[0][k], w, a0);
    a1 = fmaf(hs[1][k], w, a1);
    a2 = fmaf(hs[2][k], w, a2);
    a3 = fmaf(hs[3][k], w, a3);
  }
  vout[0 * D_MODEL + n] = a0; vout[1 * D_MODEL + n] = a1;
  vout[2 * D_MODEL + n] = a2; vout[3 * D_MODEL + n] = a3;
}

// ---- x1 = x + delta[b]; write x1 (f32) to out; LN2 -> h2 (bf16) ----
__global__ __launch_bounds__(256) void fused_res_ln(
    const float* __restrict__ x, const float* __restrict__ delta,
    const float* __restrict__ g, const float* __restrict__ be,
    float* __restrict__ x1_out, unsigned short* __restrict__ h2) {
  __shared__ float s4[4];
  int row = blockIdx.x;
  int b = row / SEQ;
  const float* xr = x + (size_t)row * D_MODEL;
  const float* dr = delta + b * D_MODEL;
  int t = threadIdx.x;
  float v[4]; float sum = 0.f;
  #pragma unroll
  for (int i = 0; i < 4; ++i) {
    int d = t + i * 256;
    v[i] = xr[d] + dr[d];
    sum += v[i];
  }
  float mean = block_sum(sum, s4) * (1.f / 1024.f);
  float sq = 0.f;
  #pragma unroll
  for (int i = 0; i < 4; ++i) { float c = v[i] - mean; sq += c * c; }
  float var = block_sum(sq, s4) * (1.f / 1023.f);
  float inv = 1.f / (sqrtf(var) + 1e-6f);
  #pragma unroll
  for (int i = 0; i < 4; ++i) {
    int d = t + i * 256;
    x1_out[(size_t)row * D_MODEL + d] = v[i];
    float hn = g[d] * (v[i] - mean) * inv + be[d];
    h2[(size_t)row * D_MODEL + d] = f2bf(hn);
  }
}

// ---- bf16 MFMA GEMM: C[M][N] = A[M][K] @ Bt[N][K]^T ----
// EPI 0: C = gelu(acc + bias) -> bf16 Cb
// EPI 1: Cf[m][n] += acc + bias  (residual already in Cf)
template <int EPI>
__global__ __launch_bounds__(256) void gemm_bf16_tn(
    const unsigned short* __restrict__ A, const unsigned short* __restrict__ Bt,
    const float* __restrict__ bias, unsigned short* __restrict__ Cb,
    float* __restrict__ Cf, int M, int N, int K) {
  __shared__ __align__(16) unsigned short As[128][40];  // +8 pad: conflict-lite
  __shared__ __align__(16) unsigned short Bs[128][40];
  int m0 = blockIdx.y * 128;
  int n0 = blockIdx.x * 128;
  int t = threadIdx.x;
  int wid = t >> 6, lane = t & 63;
  int wm = wid >> 1, wn = wid & 1;   // 2x2 wave grid, 64x64 per wave
  int lr = lane & 15;                // frag row(A)/col(B)/col(C)
  int kg = lane >> 4;                // k-group 0..3

  f32x4 acc[4][4] = {};

  int sr = t >> 2;            // staging row 0..63
  int sc = (t & 3) * 8;       // staging col {0,8,16,24}

  for (int kt = 0; kt < K; kt += 32) {
    const unsigned short* Ag = A + (size_t)(m0 + sr) * K + kt + sc;
    *(uint4*)&As[sr][sc]      = *(const uint4*)Ag;
    *(uint4*)&As[sr + 64][sc] = *(const uint4*)(Ag + (size_t)64 * K);
    const unsigned short* Bg = Bt + (size_t)(n0 + sr) * K + kt + sc;
    *(uint4*)&Bs[sr][sc]      = *(const uint4*)Bg;
    *(uint4*)&Bs[sr + 64][sc] = *(const uint4*)(Bg + (size_t)64 * K);
    __syncthreads();

    bf16x8 af[4], bf[4];
    #pragma unroll
    for (int i = 0; i < 4; ++i) {
      af[i] = *(const bf16x8*)&As[wm * 64 + i * 16 + lr][kg * 8];
      bf[i] = *(const bf16x8*)&Bs[wn * 64 + i * 16 + lr][kg * 8];
    }
    #pragma unroll
    for (int mi = 0; mi < 4; ++mi)
      #pragma unroll
      for (int ni = 0; ni < 4; ++ni)
        acc[mi][ni] = __builtin_amdgcn_mfma_f32_16x16x32_bf16(
            af[mi], bf[ni], acc[mi][ni], 0, 0, 0);
    __syncthreads();
  }

  int orow = m0 + wm * 64;
  int ocol = n0 + wn * 64;
  #pragma unroll
  for (int mi = 0; mi < 4; ++mi) {
    #pragma unroll
    for (int ni = 0; ni < 4; ++ni) {
      int col = ocol + ni * 16 + lr;
      float bz = bias[col];
      #pragma unroll
      for (int j = 0; j < 4; ++j) {
        int row = orow + mi * 16 + kg * 4 + j;   // C/D: col=lane&15, row=(lane>>4)*4+j
        float val = acc[mi][ni][j] + bz;
        if (EPI == 0) {
          val = 0.5f * val * (1.0f + erff(val * 0.70710678118f));  // exact GELU
          Cb[(size_t)row * N + col] = f2bf(val);
        } else {
          size_t idx = (size_t)row * N + col;
          Cf[idx] = Cf[idx] + val;
        }
      }
    }
  }
}

extern "C" void kernel_launch(void* const* d_in, const int* in_sizes, int n_in,
                              void* d_out, int out_size, void* d_ws, size_t ws_size,
                              hipStream_t stream) {
  const float* x    = (const float*)d_in[0];
  // d_in[1]=wq, d_in[2]=wk are dead: attention mask keeps only key 0 ->
  // softmax is exactly onehot regardless of scores.
  const float* wv   = (const float*)d_in[3];
  const float* wo   = (const float*)d_in[4];
  const float* w1   = (const float*)d_in[5];
  const float* b1   = (const float*)d_in[6];
  const float* w2   = (const float*)d_in[7];
  const float* b2   = (const float*)d_in[8];
  const float* ln1a = (const float*)d_in[9];
  const float* ln1b = (const float*)d_in[10];
  const float* ln2a = (const float*)d_in[11];
  const float* ln2b = (const float*)d_in[12];
  float* out = (float*)d_out;

  char* ws = (char*)d_ws;
  unsigned short* w1t = (unsigned short*)(ws);                       // 8 MB  [HIDDEN][D]
  unsigned short* w2t = (unsigned short*)(ws + (8ull  << 20));       // 8 MB  [D][HIDDEN]
  unsigned short* h2  = (unsigned short*)(ws + (16ull << 20));       // 16 MB [8192][1024]
  unsigned short* act = (unsigned short*)(ws + (32ull << 20));       // 64 MB [8192][4096]
  float* h0    = (float*)(ws + (96ull << 20));                       // 16 KB
  float* v0    = (float*)(ws + (96ull << 20) + 16384);               // 16 KB
  float* delta = (float*)(ws + (96ull << 20) + 32768);               // 16 KB

  // 1) weight convert+transpose: w1 [1024][4096] -> w1t [4096][1024] bf16
  transpose_cvt<<<dim3(HIDDEN / 32, D_MODEL / 32), 256, 0, stream>>>(w1, w1t, D_MODEL, HIDDEN);
  //    w2 [4096][1024] -> w2t [1024][4096] bf16
  transpose_cvt<<<dim3(D_MODEL / 32, HIDDEN / 32), 256, 0, stream>>>(w2, w2t, HIDDEN, D_MODEL);

  // 2) attention collapsed path (fp32 exact)
  ln_row0_kernel<<<BATCH, 256, 0, stream>>>(x, ln1a, ln1b, h0);
  matvec_b4<<<D_MODEL / 256, 256, 0, stream>>>(h0, wv, v0);     // v0 = h0 @ wv
  matvec_b4<<<D_MODEL / 256, 256, 0, stream>>>(v0, wo, delta);  // delta = v0 @ wo

  // 3) x1 = x + delta[b] -> out (f32); h2 = LN2(x1) -> bf16
  fused_res_ln<<<NROWS, 256, 0, stream>>>(x, delta, ln2a, ln2b, out, h2);

  // 4) act = gelu(h2 @ w1 + b1)   [8192 x 4096]
  gemm_bf16_tn<0><<<dim3(HIDDEN / 128, NROWS / 128), 256, 0, stream>>>(
      h2, w1t, b1, act, nullptr, NROWS, HIDDEN, D_MODEL);

  // 5) out += act @ w2 + b2       [8192 x 1024]
  gemm_bf16_tn<1><<<dim3(D_MODEL / 128, NROWS / 128), 256, 0, stream>>>(
      act, w2t, b2, nullptr, out, NROWS, D_MODEL, HIDDEN);
}

// Round 2
// 292.260 us; speedup vs baseline: 1.2791x; 1.2791x over previous
//
#include <hip/hip_runtime.h>
#include <cstdint>

#define D_MODEL 1024
#define HIDDEN  4096
#define BATCH   4
#define SEQ     2048
#define NROWS   (BATCH*SEQ)   // 8192

typedef __attribute__((ext_vector_type(8))) __bf16 bf16x8;
typedef __attribute__((ext_vector_type(4))) float f32x4;

#define GLDS16(g, l) __builtin_amdgcn_global_load_lds(                        \
    (const __attribute__((address_space(1))) unsigned int*)(g),               \
    (__attribute__((address_space(3))) unsigned int*)(l), 16, 0, 0)

__device__ __forceinline__ unsigned short f2bf(float f) {
  union { float f; unsigned u; } a; a.f = f;
  unsigned u = a.u;
  u += 0x7fffu + ((u >> 16) & 1u);   // round-to-nearest-even
  return (unsigned short)(u >> 16);
}

__device__ __forceinline__ float block_sum(float v, float* s4) {
  #pragma unroll
  for (int off = 32; off > 0; off >>= 1) v += __shfl_down(v, off);
  int lane = threadIdx.x & 63, wid = threadIdx.x >> 6;
  __syncthreads();
  if (lane == 0) s4[wid] = v;
  __syncthreads();
  return s4[0] + s4[1] + s4[2] + s4[3];
}

// ---- transpose + f32->bf16 convert: in [R][C] f32 -> out [C][R] bf16 ----
__global__ __launch_bounds__(256) void transpose_cvt(
    const float* __restrict__ in, unsigned short* __restrict__ out, int R, int C) {
  __shared__ float tile[32][33];
  int c0 = blockIdx.x * 32, r0 = blockIdx.y * 32;
  int tx = threadIdx.x & 31, ty = threadIdx.x >> 5;   // ty 0..7
  #pragma unroll
  for (int i = ty; i < 32; i += 8)
    tile[i][tx] = in[(size_t)(r0 + i) * C + c0 + tx];
  __syncthreads();
  #pragma unroll
  for (int i = ty; i < 32; i += 8)
    out[(size_t)(c0 + i) * R + r0 + tx] = f2bf(tile[tx][i]);
}

// ---- LN1 of row s=0 of each batch -> h0 [B][D] f32 ----
__global__ __launch_bounds__(256) void ln_row0_kernel(
    const float* __restrict__ x, const float* __restrict__ g,
    const float* __restrict__ be, float* __restrict__ h0) {
  __shared__ float s4[4];
  int b = blockIdx.x;
  const float* xr = x + (size_t)b * SEQ * D_MODEL;
  int t = threadIdx.x;
  float v[4]; float sum = 0.f;
  #pragma unroll
  for (int i = 0; i < 4; ++i) { v[i] = xr[t + i * 256]; sum += v[i]; }
  float mean = block_sum(sum, s4) * (1.f / 1024.f);
  float sq = 0.f;
  #pragma unroll
  for (int i = 0; i < 4; ++i) { float c = v[i] - mean; sq += c * c; }
  float var = block_sum(sq, s4) * (1.f / 1023.f);   // ddof=1
  float inv = 1.f / (sqrtf(var) + 1e-6f);           // eps on std
  #pragma unroll
  for (int i = 0; i < 4; ++i) {
    int d = t + i * 256;
    h0[b * D_MODEL + d] = g[d] * (v[i] - mean) * inv + be[d];
  }
}

// ---- split-K matvec: part[kc][b][n] = sum_{k in chunk kc} vin[b][k]*W[k][n] ----
#define KCHUNKS 8
#define KCH     (D_MODEL / KCHUNKS)   // 128
__global__ __launch_bounds__(256) void matvec_b4_split(
    const float* __restrict__ vin, const float* __restrict__ W,
    float* __restrict__ part) {
  int n  = blockIdx.x * 256 + threadIdx.x;
  int k0 = blockIdx.y * KCH;
  __shared__ float hs[4][KCH];
  for (int i = threadIdx.x; i < 4 * KCH; i += 256)
    hs[i >> 7][i & (KCH - 1)] = vin[(i >> 7) * D_MODEL + k0 + (i & (KCH - 1))];
  __syncthreads();
  float a0 = 0, a1 = 0, a2 = 0, a3 = 0;
  #pragma unroll 4
  for (int k = 0; k < KCH; ++k) {
    float w = W[(size_t)(k0 + k) * D_MODEL + n];
    a0 = fmaf(hs[0][k], w, a0);
    a1 = fmaf(hs[1][k], w, a1);
    a2 = fmaf(hs[2][k], w, a2);
    a3 = fmaf(hs[3][k], w, a3);
  }
  float* p = part + (size_t)blockIdx.y * 4 * D_MODEL;
  p[0 * D_MODEL + n] = a0; p[1 * D_MODEL + n] = a1;
  p[2 * D_MODEL + n] = a2; p[3 * D_MODEL + n] = a3;
}

__global__ __launch_bounds__(256) void matvec_b4_reduce(
    const float* __restrict__ part, float* __restrict__ vout) {
  int n = blockIdx.x * 256 + threadIdx.x;
  #pragma unroll
  for (int b = 0; b < 4; ++b) {
    float s = 0.f;
    #pragma unroll
    for (int kc = 0; kc < KCHUNKS; ++kc)
      s += part[((size_t)kc * 4 + b) * D_MODEL + n];
    vout[b * D_MODEL + n] = s;
  }
}

// ---- x1 = x + delta[b]; write x1 (f32) to out; LN2 -> h2 (bf16) ----
__global__ __launch_bounds__(256) void fused_res_ln(
    const float* __restrict__ x, const float* __restrict__ delta,
    const float* __restrict__ g, const float* __restrict__ be,
    float* __restrict__ x1_out, unsigned short* __restrict__ h2) {
  __shared__ float s4[4];
  int row = blockIdx.x;
  int b = row / SEQ;
  const float* xr = x + (size_t)row * D_MODEL;
  const float* dr = delta + b * D_MODEL;
  int t = threadIdx.x;
  float v[4]; float sum = 0.f;
  #pragma unroll
  for (int i = 0; i < 4; ++i) {
    int d = t + i * 256;
    v[i] = xr[d] + dr[d];
    sum += v[i];
  }
  float mean = block_sum(sum, s4) * (1.f / 1024.f);
  float sq = 0.f;
  #pragma unroll
  for (int i = 0; i < 4; ++i) { float c = v[i] - mean; sq += c * c; }
  float var = block_sum(sq, s4) * (1.f / 1023.f);
  float inv = 1.f / (sqrtf(var) + 1e-6f);
  #pragma unroll
  for (int i = 0; i < 4; ++i) {
    int d = t + i * 256;
    x1_out[(size_t)row * D_MODEL + d] = v[i];
    float hn = g[d] * (v[i] - mean) * inv + be[d];
    h2[(size_t)row * D_MODEL + d] = f2bf(hn);
  }
}

// ---- bf16 MFMA GEMM (m97 structure): C[M][N] = A[M][K] @ Bt[N][K]^T ----
// Linear LDS [128][32], global_load_lds width=16 staging.
// EPI 0: C = gelu(acc + bias) -> bf16 Cb
// EPI 1: Cf[m][n] += acc + bias  (residual already in Cf)
template <int EPI>
__global__ __launch_bounds__(256) void gemm_bf16_tn(
    const unsigned short* __restrict__ A, const unsigned short* __restrict__ Bt,
    const float* __restrict__ bias, unsigned short* __restrict__ Cb,
    float* __restrict__ Cf, int M, int N, int K) {
  __shared__ __align__(16) unsigned short As[128][32];  // linear: gl_lds needs it
  __shared__ __align__(16) unsigned short Bs[128][32];
  int m0 = blockIdx.y * 128;
  int n0 = blockIdx.x * 128;
  int t = threadIdx.x;
  int wid = t >> 6, lane = t & 63;
  int wm = wid >> 1, wn = wid & 1;   // 2x2 wave grid, 64x64 per wave
  int lr = lane & 15;                // frag row(A)/col(B)/col(C)
  int kg = lane >> 4;                // k-group 0..3

  f32x4 acc[4][4] = {};

  // staging geometry: wave w writes LDS elements [w*512 + inst*2048, +512)
  // lane covers 8 elems at w*512 + lane*8 (+inst*2048); row=elem/32, col=elem%32
  int se = wid * 512 + lane * 8;
  int sr = se >> 5;                  // row 0..31 (inst0), +64 for inst1
  int sc = se & 31;                  // col {0,8,16,24}
  const unsigned short* Ag = A + (size_t)(m0 + sr) * K + sc;
  const unsigned short* Bg = Bt + (size_t)(n0 + sr) * K + sc;
  unsigned short* ldsA0 = &As[0][0] + wid * 512;          // wave-uniform
  unsigned short* ldsA1 = &As[0][0] + wid * 512 + 2048;
  unsigned short* ldsB0 = &Bs[0][0] + wid * 512;
  unsigned short* ldsB1 = &Bs[0][0] + wid * 512 + 2048;

  for (int kt = 0; kt < K; kt += 32) {
    GLDS16(Ag + kt,                 ldsA0);
    GLDS16(Ag + (size_t)64 * K + kt, ldsA1);
    GLDS16(Bg + kt,                 ldsB0);
    GLDS16(Bg + (size_t)64 * K + kt, ldsB1);
    __syncthreads();   // drains vmcnt -> LDS tile ready

    bf16x8 af[4], bfr[4];
    #pragma unroll
    for (int i = 0; i < 4; ++i) {
      af[i]  = *(const bf16x8*)&As[wm * 64 + i * 16 + lr][kg * 8];
      bfr[i] = *(const bf16x8*)&Bs[wn * 64 + i * 16 + lr][kg * 8];
    }
    #pragma unroll
    for (int mi = 0; mi < 4; ++mi)
      #pragma unroll
      for (int ni = 0; ni < 4; ++ni)
        acc[mi][ni] = __builtin_amdgcn_mfma_f32_16x16x32_bf16(
            af[mi], bfr[ni], acc[mi][ni], 0, 0, 0);
    __syncthreads();   // all waves done reading before next overwrite
  }

  int orow = m0 + wm * 64;
  int ocol = n0 + wn * 64;
  #pragma unroll
  for (int mi = 0; mi < 4; ++mi) {
    #pragma unroll
    for (int ni = 0; ni < 4; ++ni) {
      int col = ocol + ni * 16 + lr;
      float bz = bias[col];
      #pragma unroll
      for (int j = 0; j < 4; ++j) {
        int row = orow + mi * 16 + kg * 4 + j;   // C/D: col=lane&15, row=(lane>>4)*4+j
        float val = acc[mi][ni][j] + bz;
        if (EPI == 0) {
          val = 0.5f * val * (1.0f + erff(val * 0.70710678118f));  // exact GELU
          Cb[(size_t)row * N + col] = f2bf(val);
        } else {
          size_t idx = (size_t)row * N + col;
          Cf[idx] = Cf[idx] + val;
        }
      }
    }
  }
}

extern "C" void kernel_launch(void* const* d_in, const int* in_sizes, int n_in,
                              void* d_out, int out_size, void* d_ws, size_t ws_size,
                              hipStream_t stream) {
  const float* x    = (const float*)d_in[0];
  // d_in[1]=wq, d_in[2]=wk are dead: attention mask keeps only key 0 ->
  // softmax is exactly onehot regardless of scores.
  const float* wv   = (const float*)d_in[3];
  const float* wo   = (const float*)d_in[4];
  const float* w1   = (const float*)d_in[5];
  const float* b1   = (const float*)d_in[6];
  const float* w2   = (const float*)d_in[7];
  const float* b2   = (const float*)d_in[8];
  const float* ln1a = (const float*)d_in[9];
  const float* ln1b = (const float*)d_in[10];
  const float* ln2a = (const float*)d_in[11];
  const float* ln2b = (const float*)d_in[12];
  float* out = (float*)d_out;

  char* ws = (char*)d_ws;
  unsigned short* w1t = (unsigned short*)(ws);                       // 8 MB  [HIDDEN][D]
  unsigned short* w2t = (unsigned short*)(ws + (8ull  << 20));       // 8 MB  [D][HIDDEN]
  unsigned short* h2  = (unsigned short*)(ws + (16ull << 20));       // 16 MB [8192][1024]
  unsigned short* act = (unsigned short*)(ws + (32ull << 20));       // 64 MB [8192][4096]
  float* h0    = (float*)(ws + (96ull << 20));                       // 16 KB
  float* v0    = (float*)(ws + (96ull << 20) + 16384);               // 16 KB
  float* delta = (float*)(ws + (96ull << 20) + 32768);               // 16 KB
  float* part  = (float*)(ws + (96ull << 20) + 65536);               // 128 KB

  // 1) weight convert+transpose: w1 [1024][4096] -> w1t [4096][1024] bf16
  transpose_cvt<<<dim3(HIDDEN / 32, D_MODEL / 32), 256, 0, stream>>>(w1, w1t, D_MODEL, HIDDEN);
  //    w2 [4096][1024] -> w2t [1024][4096] bf16
  transpose_cvt<<<dim3(D_MODEL / 32, HIDDEN / 32), 256, 0, stream>>>(w2, w2t, HIDDEN, D_MODEL);

  // 2) attention collapsed path (fp32 exact), split-K matvecs
  ln_row0_kernel<<<BATCH, 256, 0, stream>>>(x, ln1a, ln1b, h0);
  matvec_b4_split<<<dim3(D_MODEL / 256, KCHUNKS), 256, 0, stream>>>(h0, wv, part);
  matvec_b4_reduce<<<D_MODEL / 256, 256, 0, stream>>>(part, v0);       // v0 = h0 @ wv
  matvec_b4_split<<<dim3(D_MODEL / 256, KCHUNKS), 256, 0, stream>>>(v0, wo, part);
  matvec_b4_reduce<<<D_MODEL / 256, 256, 0, stream>>>(part, delta);    // delta = v0 @ wo

  // 3) x1 = x + delta[b] -> out (f32); h2 = LN2(x1) -> bf16
  fused_res_ln<<<NROWS, 256, 0, stream>>>(x, delta, ln2a, ln2b, out, h2);

  // 4) act = gelu(h2 @ w1 + b1)   [8192 x 4096]
  gemm_bf16_tn<0><<<dim3(HIDDEN / 128, NROWS / 128), 256, 0, stream>>>(
      h2, w1t, b1, act, nullptr, NROWS, HIDDEN, D_MODEL);

  // 5) out += act @ w2 + b2       [8192 x 1024]
  gemm_bf16_tn<1><<<dim3(D_MODEL / 128, NROWS / 128), 256, 0, stream>>>(
      act, w2t, b2, nullptr, out, NROWS, D_MODEL, HIDDEN);
}

// Round 3
// 255.550 us; speedup vs baseline: 1.4628x; 1.1437x over previous
//
#include <hip/hip_runtime.h>
#include <cstdint>

#define D_MODEL 1024
#define HIDDEN  4096
#define BATCH   4
#define SEQ     2048
#define NROWS   (BATCH*SEQ)   // 8192

typedef __attribute__((ext_vector_type(8))) __bf16 bf16x8;
typedef __attribute__((ext_vector_type(4))) float f32x4;

#define GLDS16(g, l) __builtin_amdgcn_global_load_lds(                        \
    (const __attribute__((address_space(1))) unsigned int*)(g),               \
    (__attribute__((address_space(3))) unsigned int*)(l), 16, 0, 0)

__device__ __forceinline__ unsigned short f2bf(float f) {
  union { float f; unsigned u; } a; a.f = f;
  unsigned u = a.u;
  u += 0x7fffu + ((u >> 16) & 1u);   // round-to-nearest-even
  return (unsigned short)(u >> 16);
}

__device__ __forceinline__ float block_sum(float v, float* s4) {
  #pragma unroll
  for (int off = 32; off > 0; off >>= 1) v += __shfl_down(v, off);
  int lane = threadIdx.x & 63, wid = threadIdx.x >> 6;
  __syncthreads();
  if (lane == 0) s4[wid] = v;
  __syncthreads();
  return s4[0] + s4[1] + s4[2] + s4[3];
}

// ---- transpose + f32->bf16 convert: in [R][C] f32 -> out [C][R] bf16 ----
__global__ __launch_bounds__(256) void transpose_cvt(
    const float* __restrict__ in, unsigned short* __restrict__ out, int R, int C) {
  __shared__ float tile[32][33];
  int c0 = blockIdx.x * 32, r0 = blockIdx.y * 32;
  int tx = threadIdx.x & 31, ty = threadIdx.x >> 5;   // ty 0..7
  #pragma unroll
  for (int i = ty; i < 32; i += 8)
    tile[i][tx] = in[(size_t)(r0 + i) * C + c0 + tx];
  __syncthreads();
  #pragma unroll
  for (int i = ty; i < 32; i += 8)
    out[(size_t)(c0 + i) * R + r0 + tx] = f2bf(tile[tx][i]);
}

// ---- LN1 of row s=0 of each batch -> h0 [B][D] f32 ----
__global__ __launch_bounds__(256) void ln_row0_kernel(
    const float* __restrict__ x, const float* __restrict__ g,
    const float* __restrict__ be, float* __restrict__ h0) {
  __shared__ float s4[4];
  int b = blockIdx.x;
  const float* xr = x + (size_t)b * SEQ * D_MODEL;
  int t = threadIdx.x;
  float v[4]; float sum = 0.f;
  #pragma unroll
  for (int i = 0; i < 4; ++i) { v[i] = xr[t + i * 256]; sum += v[i]; }
  float mean = block_sum(sum, s4) * (1.f / 1024.f);
  float sq = 0.f;
  #pragma unroll
  for (int i = 0; i < 4; ++i) { float c = v[i] - mean; sq += c * c; }
  float var = block_sum(sq, s4) * (1.f / 1023.f);   // ddof=1
  float inv = 1.f / (sqrtf(var) + 1e-6f);           // eps on std
  #pragma unroll
  for (int i = 0; i < 4; ++i) {
    int d = t + i * 256;
    h0[b * D_MODEL + d] = g[d] * (v[i] - mean) * inv + be[d];
  }
}

// ---- split-K matvec: part[kc][b][n] = sum_{k in chunk kc} vin[b][k]*W[k][n] ----
#define KCHUNKS 8
#define KCH     (D_MODEL / KCHUNKS)   // 128
__global__ __launch_bounds__(256) void matvec_b4_split(
    const float* __restrict__ vin, const float* __restrict__ W,
    float* __restrict__ part) {
  int n  = blockIdx.x * 256 + threadIdx.x;
  int k0 = blockIdx.y * KCH;
  __shared__ float hs[4][KCH];
  for (int i = threadIdx.x; i < 4 * KCH; i += 256)
    hs[i >> 7][i & (KCH - 1)] = vin[(i >> 7) * D_MODEL + k0 + (i & (KCH - 1))];
  __syncthreads();
  float a0 = 0, a1 = 0, a2 = 0, a3 = 0;
  #pragma unroll 4
  for (int k = 0; k < KCH; ++k) {
    float w = W[(size_t)(k0 + k) * D_MODEL + n];
    a0 = fmaf(hs[0][k], w, a0);
    a1 = fmaf(hs[1][k], w, a1);
    a2 = fmaf(hs[2][k], w, a2);
    a3 = fmaf(hs[3][k], w, a3);
  }
  float* p = part + (size_t)blockIdx.y * 4 * D_MODEL;
  p[0 * D_MODEL + n] = a0; p[1 * D_MODEL + n] = a1;
  p[2 * D_MODEL + n] = a2; p[3 * D_MODEL + n] = a3;
}

__global__ __launch_bounds__(256) void matvec_b4_reduce(
    const float* __restrict__ part, float* __restrict__ vout) {
  int n = blockIdx.x * 256 + threadIdx.x;
  #pragma unroll
  for (int b = 0; b < 4; ++b) {
    float s = 0.f;
    #pragma unroll
    for (int kc = 0; kc < KCHUNKS; ++kc)
      s += part[((size_t)kc * 4 + b) * D_MODEL + n];
    vout[b * D_MODEL + n] = s;
  }
}

// ---- x1 = x + delta[b]; write x1 (f32) to out; LN2 -> h2 (bf16) ----
__global__ __launch_bounds__(256) void fused_res_ln(
    const float* __restrict__ x, const float* __restrict__ delta,
    const float* __restrict__ g, const float* __restrict__ be,
    float* __restrict__ x1_out, unsigned short* __restrict__ h2) {
  __shared__ float s4[4];
  int row = blockIdx.x;
  int b = row / SEQ;
  const float* xr = x + (size_t)row * D_MODEL;
  const float* dr = delta + b * D_MODEL;
  int t = threadIdx.x;
  float v[4]; float sum = 0.f;
  #pragma unroll
  for (int i = 0; i < 4; ++i) {
    int d = t + i * 256;
    v[i] = xr[d] + dr[d];
    sum += v[i];
  }
  float mean = block_sum(sum, s4) * (1.f / 1024.f);
  float sq = 0.f;
  #pragma unroll
  for (int i = 0; i < 4; ++i) { float c = v[i] - mean; sq += c * c; }
  float var = block_sum(sq, s4) * (1.f / 1023.f);
  float inv = 1.f / (sqrtf(var) + 1e-6f);
  #pragma unroll
  for (int i = 0; i < 4; ++i) {
    int d = t + i * 256;
    x1_out[(size_t)row * D_MODEL + d] = v[i];
    float hn = g[d] * (v[i] - mean) * inv + be[d];
    h2[(size_t)row * D_MODEL + d] = f2bf(hn);
  }
}

// ============================================================================
// 8-phase 256-wide-tile bf16 GEMM (m201 template, plain HIP).
// C[M][N] = A[M][K] @ Bt[N][K]^T.  BM=256, BK=64, 8 waves (2M x 4N), 512 thr.
// T2: XOR swizzle col^((row&7)<<3), applied at global SOURCE (gload_lds writes
//     linear) and at ds_read.  T4: counted vmcnt, one checkpoint per K-tile.
// T5: setprio around MFMA clusters.
// Schedule per K-tile group (4 phases), slot s = G&1, reads tile G:
//   r1: readA(mh0) + readB(nh0)                     -> MFMA (mh0,nh0)
//   r2: readB(nh1)                                  -> MFMA (mh0,nh1)
//   r3: readA(mh1) + stage B halves of tile G+2     -> MFMA (mh1,nh1)
//   r4: stage A halves of tile G+2, MFMA (mh1,nh0), vmcnt(VM)
// B halves consumed end r2, A halves end r3 -> r3/r4 stages never overwrite
// live data.  vmcnt(VM=4+2*BLJ) leaves only r3+r4's own stages outstanding ->
// tile G+1 (staged last group) guaranteed landed before next group reads it.
// ============================================================================
template <int EPI, int BN>
__global__ __launch_bounds__(512, 2) void gemm8p(
    const unsigned short* __restrict__ A, const unsigned short* __restrict__ Bt,
    const float* __restrict__ bias, unsigned short* __restrict__ Cb,
    float* __restrict__ Cf, int M, int N, int K) {
  constexpr int BM  = 256, BK = 64;
  constexpr int NFN = BN / 64;       // n-frags per wave (4 or 2)
  constexpr int PNF = NFN / 2;       // n-frags per phase (2 or 1)
  constexpr int BHR = BN / 2;        // B half rows (128 or 64)
  constexpr int BLJ = BN / 128;      // B gloads per half per thread (2 or 1)
  constexpr int VM  = 4 + 2 * BLJ;   // vmcnt at checkpoints (8 or 6)

  __shared__ unsigned short As[2][2][128][64];      // [slot][half][row][col]
  __shared__ unsigned short Bs[2][2][BHR][64];

  int GN  = N / BN;
  int nwg = (M / BM) * GN;
  int id  = blockIdx.x;
  int sw  = (id & 7) * (nwg >> 3) + (id >> 3);      // XCD-aware swizzle
  int by  = sw / GN, bx = sw % GN;
  int m0  = by * BM, n0 = bx * BN;

  int t = threadIdx.x;
  int wid = t >> 6, lane = t & 63;
  int wm = wid >> 2, wn = wid & 3;     // wave grid 2M x 4N
  int lr = lane & 15, kg = lane >> 4;
  int swz = (lr & 7) << 3;             // read-side XOR (elements)

  int NT = K / BK;                     // K-tiles

  // staging geometry: thread covers LDS elems t*8 (+j*4096 per 64-row chunk)
  int rA = t >> 3;                                   // 0..63
  int cS = 8 * ((t & 7) ^ ((t >> 3) & 7));           // pre-swizzled src col
  const unsigned short* Ag = A  + (size_t)(m0 + rA) * K + cS;
  const unsigned short* Bg = Bt + (size_t)(n0 + rA) * K + cS;
  int ldsOff = wid * 512;   // elements; wave-uniform; lane*16B added by HW

#define STAGE_A(s, T) do {                                                     \
    size_t kofs_ = (size_t)(T) * 64;                                           \
    GLDS16(Ag + kofs_,                    &As[s][0][0][0] + ldsOff);           \
    GLDS16(Ag + kofs_ + (size_t)64  * K,  &As[s][0][0][0] + ldsOff + 4096);    \
    GLDS16(Ag + kofs_ + (size_t)128 * K,  &As[s][1][0][0] + ldsOff);           \
    GLDS16(Ag + kofs_ + (size_t)192 * K,  &As[s][1][0][0] + ldsOff + 4096);    \
  } while (0)

#define STAGE_B(s, T) do {                                                     \
    size_t kofs_ = (size_t)(T) * 64;                                           \
    if (BN == 256) {                                                           \
      GLDS16(Bg + kofs_,                    &Bs[s][0][0][0] + ldsOff);         \
      GLDS16(Bg + kofs_ + (size_t)64  * K,  &Bs[s][0][0][0] + ldsOff + 4096);  \
      GLDS16(Bg + kofs_ + (size_t)128 * K,  &Bs[s][1][0][0] + ldsOff);         \
      GLDS16(Bg + kofs_ + (size_t)192 * K,  &Bs[s][1][0][0] + ldsOff + 4096);  \
    } else {                                                                   \
      GLDS16(Bg + kofs_,                    &Bs[s][0][0][0] + ldsOff);         \
      GLDS16(Bg + kofs_ + (size_t)64  * K,  &Bs[s][1][0][0] + ldsOff);         \
    }                                                                          \
  } while (0)

#define WAITVM() do {                                                          \
    if (VM == 8) asm volatile("s_waitcnt vmcnt(8)" ::: "memory");              \
    else         asm volatile("s_waitcnt vmcnt(6)" ::: "memory");              \
  } while (0)

#define READ_A(s, mh) do {                                                     \
    _Pragma("unroll") for (int mi = 0; mi < 4; ++mi)                           \
    _Pragma("unroll") for (int kk = 0; kk < 2; ++kk)                           \
      a[mi][kk] = *(const bf16x8*)                                             \
          &As[s][wm][(mh) * 64 + mi * 16 + lr][(kk * 32 + kg * 8) ^ swz];      \
  } while (0)

#define READ_B(s, nh) do {                                                     \
    _Pragma("unroll") for (int ni = 0; ni < PNF; ++ni)                         \
    _Pragma("unroll") for (int kk = 0; kk < 2; ++kk)                           \
      b[nh][ni][kk] = *(const bf16x8*)                                         \
          &Bs[s][wn >> 1][(wn & 1) * (BN / 4) + ((nh) * PNF + ni) * 16 + lr]   \
             [(kk * 32 + kg * 8) ^ swz];                                       \
  } while (0)

#define MFMA_Q(mh, nh) do {                                                    \
    _Pragma("unroll") for (int mi = 0; mi < 4; ++mi)                           \
    _Pragma("unroll") for (int ni = 0; ni < PNF; ++ni)                         \
    _Pragma("unroll") for (int kk = 0; kk < 2; ++kk)                           \
      acc[(mh) * 4 + mi][(nh) * PNF + ni] =                                    \
          __builtin_amdgcn_mfma_f32_16x16x32_bf16(                             \
              a[mi][kk], b[nh][ni][kk], acc[(mh) * 4 + mi][(nh) * PNF + ni],   \
              0, 0, 0);                                                        \
  } while (0)

#define GROUP(s, G) do {                                                       \
    int Tn_ = (G) + 2; if (Tn_ > NT - 1) Tn_ = NT - 1;                         \
    /* r1 */                                                                   \
    READ_A(s, 0); READ_B(s, 0);                                                \
    asm volatile("s_waitcnt lgkmcnt(8)" ::: "memory");                         \
    __builtin_amdgcn_s_barrier();                                              \
    asm volatile("s_waitcnt lgkmcnt(0)" ::: "memory");                         \
    __builtin_amdgcn_s_setprio(1); MFMA_Q(0, 0); __builtin_amdgcn_s_setprio(0);\
    __builtin_amdgcn_s_barrier();                                              \
    /* r2 */                                                                   \
    READ_B(s, 1);                                                              \
    __builtin_amdgcn_s_barrier();                                              \
    asm volatile("s_waitcnt lgkmcnt(0)" ::: "memory");                         \
    __builtin_amdgcn_s_setprio(1); MFMA_Q(0, 1); __builtin_amdgcn_s_setprio(0);\
    __builtin_amdgcn_s_barrier();                                              \
    /* r3 */                                                                   \
    READ_A(s, 1); STAGE_B(s, Tn_);                                             \
    __builtin_amdgcn_s_barrier();                                              \
    asm volatile("s_waitcnt lgkmcnt(0)" ::: "memory");                         \
    __builtin_amdgcn_s_setprio(1); MFMA_Q(1, 1); __builtin_amdgcn_s_setprio(0);\
    __builtin_amdgcn_s_barrier();                                              \
    /* r4 */                                                                   \
    STAGE_A(s, Tn_);                                                           \
    __builtin_amdgcn_s_barrier();                                              \
    __builtin_amdgcn_s_setprio(1); MFMA_Q(1, 0); __builtin_amdgcn_s_setprio(0);\
    WAITVM();                                                                  \
    __builtin_amdgcn_s_barrier();                                              \
  } while (0)

  f32x4 acc[8][NFN] = {};
  bf16x8 a[4][2];
  bf16x8 b[2][PNF][2];

  // prologue: tiles 0 -> slot0, 1 -> slot1; wait until tile0 landed
  STAGE_B(0, 0); STAGE_A(0, 0);
  STAGE_B(1, 1); STAGE_A(1, 1);
  WAITVM();
  __builtin_amdgcn_s_barrier();

  for (int G = 0; G < NT; G += 2) {
    GROUP(0, G);
    GROUP(1, G + 1);
  }
  asm volatile("s_waitcnt vmcnt(0)" ::: "memory");  // drain clamped tail stages

  // epilogue
  int orow = m0 + wm * 128;
  int ocol = n0 + wn * (BN / 4);
  #pragma unroll
  for (int mf = 0; mf < 8; ++mf) {
    #pragma unroll
    for (int nf = 0; nf < NFN; ++nf) {
      int col = ocol + nf * 16 + lr;
      float bz = bias[col];
      #pragma unroll
      for (int j = 0; j < 4; ++j) {
        int row = orow + mf * 16 + kg * 4 + j;   // C/D: col=lane&15, row=(lane>>4)*4+j
        float val = acc[mf][nf][j] + bz;
        if (EPI == 0) {
          val = 0.5f * val * (1.0f + erff(val * 0.70710678118f));  // exact GELU
          Cb[(size_t)row * N + col] = f2bf(val);
        } else {
          size_t idx = (size_t)row * N + col;
          Cf[idx] = Cf[idx] + val;
        }
      }
    }
  }
#undef STAGE_A
#undef STAGE_B
#undef WAITVM
#undef READ_A
#undef READ_B
#undef MFMA_Q
#undef GROUP
}

extern "C" void kernel_launch(void* const* d_in, const int* in_sizes, int n_in,
                              void* d_out, int out_size, void* d_ws, size_t ws_size,
                              hipStream_t stream) {
  const float* x    = (const float*)d_in[0];
  // d_in[1]=wq, d_in[2]=wk are dead: attention mask keeps only key 0 ->
  // softmax is exactly onehot regardless of scores.
  const float* wv   = (const float*)d_in[3];
  const float* wo   = (const float*)d_in[4];
  const float* w1   = (const float*)d_in[5];
  const float* b1   = (const float*)d_in[6];
  const float* w2   = (const float*)d_in[7];
  const float* b2   = (const float*)d_in[8];
  const float* ln1a = (const float*)d_in[9];
  const float* ln1b = (const float*)d_in[10];
  const float* ln2a = (const float*)d_in[11];
  const float* ln2b = (const float*)d_in[12];
  float* out = (float*)d_out;

  char* ws = (char*)d_ws;
  unsigned short* w1t = (unsigned short*)(ws);                       // 8 MB  [HIDDEN][D]
  unsigned short* w2t = (unsigned short*)(ws + (8ull  << 20));       // 8 MB  [D][HIDDEN]
  unsigned short* h2  = (unsigned short*)(ws + (16ull << 20));       // 16 MB [8192][1024]
  unsigned short* act = (unsigned short*)(ws + (32ull << 20));       // 64 MB [8192][4096]
  float* h0    = (float*)(ws + (96ull << 20));                       // 16 KB
  float* v0    = (float*)(ws + (96ull << 20) + 16384);               // 16 KB
  float* delta = (float*)(ws + (96ull << 20) + 32768);               // 16 KB
  float* part  = (float*)(ws + (96ull << 20) + 65536);               // 128 KB

  // 1) weight convert+transpose
  transpose_cvt<<<dim3(HIDDEN / 32, D_MODEL / 32), 256, 0, stream>>>(w1, w1t, D_MODEL, HIDDEN);
  transpose_cvt<<<dim3(D_MODEL / 32, HIDDEN / 32), 256, 0, stream>>>(w2, w2t, HIDDEN, D_MODEL);

  // 2) attention collapsed path (fp32 exact), split-K matvecs
  ln_row0_kernel<<<BATCH, 256, 0, stream>>>(x, ln1a, ln1b, h0);
  matvec_b4_split<<<dim3(D_MODEL / 256, KCHUNKS), 256, 0, stream>>>(h0, wv, part);
  matvec_b4_reduce<<<D_MODEL / 256, 256, 0, stream>>>(part, v0);       // v0 = h0 @ wv
  matvec_b4_split<<<dim3(D_MODEL / 256, KCHUNKS), 256, 0, stream>>>(v0, wo, part);
  matvec_b4_reduce<<<D_MODEL / 256, 256, 0, stream>>>(part, delta);    // delta = v0 @ wo

  // 3) x1 = x + delta[b] -> out (f32); h2 = LN2(x1) -> bf16
  fused_res_ln<<<NROWS, 256, 0, stream>>>(x, delta, ln2a, ln2b, out, h2);

  // 4) act = gelu(h2 @ w1 + b1)   [8192 x 4096], 256x256 tiles, 512 blocks
  gemm8p<0, 256><<<(NROWS / 256) * (HIDDEN / 256), 512, 0, stream>>>(
      h2, w1t, b1, act, nullptr, NROWS, HIDDEN, D_MODEL);

  // 5) out += act @ w2 + b2       [8192 x 1024], 256x128 tiles, 256 blocks
  gemm8p<1, 128><<<(NROWS / 256) * (D_MODEL / 128), 512, 0, stream>>>(
      act, w2t, b2, nullptr, out, NROWS, D_MODEL, HIDDEN);
}